// Round 1
// baseline (485.032 us; speedup 1.0000x reference)
//
#include <hip/hip_runtime.h>

#define N_NODES 100000
#define N_EDGES 600000
#define EMBED_DIM 128
#define EPSF 1e-12f

// ---------------- CSR build ----------------

__global__ void hist_kernel(const int* __restrict__ head, int* __restrict__ cnt, int E) {
    int e = blockIdx.x * blockDim.x + threadIdx.x;
    if (e < E) atomicAdd(&cnt[head[e]], 1);
}

// Single-block exclusive scan over cnt[0..N) -> row_ptr[0..N]
__global__ void scan_kernel(const int* __restrict__ cnt, int* __restrict__ row_ptr, int N) {
    __shared__ int part[1024];
    const int tid   = threadIdx.x;
    const int chunk = (N + 1023) >> 10;
    const int start = tid * chunk;
    const int end   = min(start + chunk, N);
    int s = 0;
    for (int i = start; i < end; ++i) s += cnt[i];
    part[tid] = s;
    __syncthreads();
    // Hillis-Steele inclusive scan of partials
    for (int off = 1; off < 1024; off <<= 1) {
        int v = (tid >= off) ? part[tid - off] : 0;
        __syncthreads();
        part[tid] += v;
        __syncthreads();
    }
    int run = (tid == 0) ? 0 : part[tid - 1];  // exclusive prefix of this chunk
    for (int i = start; i < end; ++i) { row_ptr[i] = run; run += cnt[i]; }
    if (end == N) row_ptr[N] = run;  // every thread whose chunk reaches/passes N writes the total
}

// Scatter each edge into its CSR slot as packed (tail | rel<<20).
// tail < 2^17, rel < 2^5 -> fits 32 bits.
__global__ void fill_kernel(const int* __restrict__ head, const int* __restrict__ tail,
                            const int* __restrict__ etype, const int* __restrict__ row_ptr,
                            int* __restrict__ fill, int* __restrict__ packed, int E) {
    int e = blockIdx.x * blockDim.x + threadIdx.x;
    if (e < E) {
        int h    = head[e];
        int slot = row_ptr[h] + atomicAdd(&fill[h], 1);
        packed[slot] = tail[e] | (etype[e] << 20);
    }
}

// ---------------- fused hop ----------------
// One wave (64 lanes) per node; each lane owns 2 dims (float2).
// acc = sum_e x[tail_e] * rel[type_e]; mean; l2-normalize; write x_new; res += / res = ego +.

template <bool FIRST>
__global__ __launch_bounds__(256) void hop_kernel(
    const float* __restrict__ x, const float* __restrict__ rel,
    const int* __restrict__ row_ptr, const int* __restrict__ packed,
    const float* __restrict__ base,   // ego (FIRST only)
    float* __restrict__ xn, float* __restrict__ res, int N) {

    const int wave = (int)((blockIdx.x * blockDim.x + threadIdx.x) >> 6);
    const int lane = threadIdx.x & 63;
    if (wave >= N) return;

    const int beg = row_ptr[wave];
    const int end = row_ptr[wave + 1];

    const float2* __restrict__ x2   = (const float2*)x;
    const float2* __restrict__ rel2 = (const float2*)rel;

    float2 acc = make_float2(0.f, 0.f);
    for (int i = beg; i < end; ++i) {
        int p = packed[i];            // wave-uniform -> scalar load
        int t = p & 0xFFFFF;
        int r = p >> 20;
        float2 xv = x2[t * 64 + lane];
        float2 rv = rel2[r * 64 + lane];
        acc.x = fmaf(xv.x, rv.x, acc.x);
        acc.y = fmaf(xv.y, rv.y, acc.y);
    }

    const int deg = end - beg;
    const float inv = 1.0f / (float)max(deg, 1);
    acc.x *= inv; acc.y *= inv;

    float ss = acc.x * acc.x + acc.y * acc.y;
    #pragma unroll
    for (int off = 32; off; off >>= 1) ss += __shfl_xor(ss, off, 64);

    const float scale = 1.0f / fmaxf(sqrtf(ss), EPSF);
    float2 v = make_float2(acc.x * scale, acc.y * scale);

    const int idx = wave * 64 + lane;
    ((float2*)xn)[idx] = v;

    float2* res2 = (float2*)res;
    if (FIRST) {
        float2 b = ((const float2*)base)[idx];
        res2[idx] = make_float2(b.x + v.x, b.y + v.y);
    } else {
        float2 r0 = res2[idx];
        res2[idx] = make_float2(r0.x + v.x, r0.y + v.y);
    }
}

// ---------------- launch ----------------

extern "C" void kernel_launch(void* const* d_in, const int* in_sizes, int n_in,
                              void* d_out, int out_size, void* d_ws, size_t ws_size,
                              hipStream_t stream) {
    const float* ego   = (const float*)d_in[0];
    const int*   eidx  = (const int*)d_in[1];   // [2, E]: row 0 = head, row 1 = tail
    const int*   etype = (const int*)d_in[2];
    const float* rel   = (const float*)d_in[3];
    // d_in[4] = dropout scalar (0 in eval) -> ignored

    const int* head = eidx;
    const int* tail = eidx + N_EDGES;
    float* res = (float*)d_out;

    // workspace layout
    char* ws = (char*)d_ws;
    int* cnt     = (int*)ws;  ws += (size_t)N_NODES * sizeof(int);
    int* row_ptr = (int*)ws;  ws += (size_t)(N_NODES + 1) * sizeof(int);
    int* fill    = (int*)ws;  ws += (size_t)N_NODES * sizeof(int);
    int* packed  = (int*)ws;  ws += (size_t)N_EDGES * sizeof(int);
    ws = (char*)(((uintptr_t)ws + 255) & ~(uintptr_t)255);
    float* x0 = (float*)ws;   ws += (size_t)N_NODES * EMBED_DIM * sizeof(float);
    float* x1 = (float*)ws;

    hipMemsetAsync(cnt,  0, (size_t)N_NODES * sizeof(int), stream);
    hipMemsetAsync(fill, 0, (size_t)N_NODES * sizeof(int), stream);

    const int eblocks = (N_EDGES + 255) / 256;
    hist_kernel<<<eblocks, 256, 0, stream>>>(head, cnt, N_EDGES);
    scan_kernel<<<1, 1024, 0, stream>>>(cnt, row_ptr, N_NODES);
    fill_kernel<<<eblocks, 256, 0, stream>>>(head, tail, etype, row_ptr, fill, packed, N_EDGES);

    // one wave per node
    const int nthreads = N_NODES * 64;
    const int nblocks  = (nthreads + 255) / 256;
    hop_kernel<true ><<<nblocks, 256, 0, stream>>>(ego, rel, row_ptr, packed, ego, x0, res, N_NODES);
    hop_kernel<false><<<nblocks, 256, 0, stream>>>(x0,  rel, row_ptr, packed, nullptr, x1, res, N_NODES);
    hop_kernel<false><<<nblocks, 256, 0, stream>>>(x1,  rel, row_ptr, packed, nullptr, x0, res, N_NODES);
}

// Round 7
// 330.200 us; speedup vs baseline: 1.4689x; 1.4689x over previous
//
#include <hip/hip_runtime.h>

#define N_NODES 100000
#define N_EDGES 600000
#define EMBED_DIM 128
#define EPSF 1e-12f

#define SCAN_NBLK ((N_NODES + 255) / 256)   // 391

// ---------------- CSR build ----------------

__global__ void hist_kernel(const int* __restrict__ head, int* __restrict__ cnt, int E) {
    int e = blockIdx.x * blockDim.x + threadIdx.x;
    if (e < E) atomicAdd(&cnt[head[e]], 1);
}

// Pass 1: per-block sums of cnt
__global__ void scan_part(const int* __restrict__ cnt, int* __restrict__ bsum, int N) {
    __shared__ int lds[256];
    const int t = threadIdx.x;
    const int i = blockIdx.x * 256 + t;
    lds[t] = (i < N) ? cnt[i] : 0;
    __syncthreads();
    for (int off = 128; off; off >>= 1) {
        if (t < off) lds[t] += lds[t + off];
        __syncthreads();
    }
    if (t == 0) bsum[blockIdx.x] = lds[0];
}

// Pass 2: single small block turns bsum into exclusive block offsets (nb <= 512)
__global__ void scan_bsum(int* __restrict__ bsum, int nb) {
    __shared__ int lds[512];
    const int t = threadIdx.x;
    const int v = (t < nb) ? bsum[t] : 0;
    lds[t] = v;
    __syncthreads();
    for (int off = 1; off < 512; off <<= 1) {
        int u = (t >= off) ? lds[t - off] : 0;
        __syncthreads();
        lds[t] += u;
        __syncthreads();
    }
    if (t < nb) bsum[t] = lds[t] - v;   // exclusive
}

// Pass 3: block-local exclusive scan + block offset -> row_ptr
__global__ void scan_final(const int* __restrict__ cnt, const int* __restrict__ bsum,
                           int* __restrict__ row_ptr, int N) {
    __shared__ int lds[256];
    const int t = threadIdx.x;
    const int i = blockIdx.x * 256 + t;
    const int v = (i < N) ? cnt[i] : 0;
    lds[t] = v;
    __syncthreads();
    for (int off = 1; off < 256; off <<= 1) {
        int u = (t >= off) ? lds[t - off] : 0;
        __syncthreads();
        lds[t] += u;
        __syncthreads();
    }
    const int excl = lds[t] - v + bsum[blockIdx.x];
    if (i < N) row_ptr[i] = excl;
    if (i == N - 1) row_ptr[N] = excl + v;
}

// Scatter each edge into its CSR slot as packed (tail | rel<<20).
__global__ void fill_kernel(const int* __restrict__ head, const int* __restrict__ tail,
                            const int* __restrict__ etype, const int* __restrict__ row_ptr,
                            int* __restrict__ fill, int* __restrict__ packed, int E) {
    int e = blockIdx.x * blockDim.x + threadIdx.x;
    if (e < E) {
        int h    = head[e];
        int slot = row_ptr[h] + atomicAdd(&fill[h], 1);
        packed[slot] = tail[e] | (etype[e] << 20);
    }
}

// ---------------- fused hop ----------------
// One wave (64 lanes) per node; each lane owns 2 dims (float2).

template <bool FIRST>
__global__ __launch_bounds__(256) void hop_kernel(
    const float* __restrict__ x, const float* __restrict__ rel,
    const int* __restrict__ row_ptr, const int* __restrict__ packed,
    const float* __restrict__ base,   // ego (FIRST only)
    float* __restrict__ xn, float* __restrict__ res, int N) {

    const int wave = (int)((blockIdx.x * blockDim.x + threadIdx.x) >> 6);
    const int lane = threadIdx.x & 63;
    if (wave >= N) return;

    const int beg = row_ptr[wave];
    const int end = row_ptr[wave + 1];

    const float2* __restrict__ x2   = (const float2*)x;
    const float2* __restrict__ rel2 = (const float2*)rel;

    float2 acc = make_float2(0.f, 0.f);
    for (int i = beg; i < end; ++i) {
        int p = packed[i];
        int t = p & 0xFFFFF;
        int r = p >> 20;
        float2 xv = x2[t * 64 + lane];
        float2 rv = rel2[r * 64 + lane];
        acc.x = fmaf(xv.x, rv.x, acc.x);
        acc.y = fmaf(xv.y, rv.y, acc.y);
    }

    const int deg = end - beg;
    const float inv = 1.0f / (float)max(deg, 1);
    acc.x *= inv; acc.y *= inv;

    float ss = acc.x * acc.x + acc.y * acc.y;
    #pragma unroll
    for (int off = 32; off; off >>= 1) ss += __shfl_xor(ss, off, 64);

    const float scale = 1.0f / fmaxf(sqrtf(ss), EPSF);
    float2 v = make_float2(acc.x * scale, acc.y * scale);

    const int idx = wave * 64 + lane;
    ((float2*)xn)[idx] = v;

    float2* res2 = (float2*)res;
    if (FIRST) {
        float2 b = ((const float2*)base)[idx];
        res2[idx] = make_float2(b.x + v.x, b.y + v.y);
    } else {
        float2 r0 = res2[idx];
        res2[idx] = make_float2(r0.x + v.x, r0.y + v.y);
    }
}

// ---------------- launch ----------------

extern "C" void kernel_launch(void* const* d_in, const int* in_sizes, int n_in,
                              void* d_out, int out_size, void* d_ws, size_t ws_size,
                              hipStream_t stream) {
    const float* ego   = (const float*)d_in[0];
    const int*   eidx  = (const int*)d_in[1];   // [2, E]: row 0 = head, row 1 = tail
    const int*   etype = (const int*)d_in[2];
    const float* rel   = (const float*)d_in[3];
    // d_in[4] = dropout scalar (0 in eval) -> ignored

    const int* head = eidx;
    const int* tail = eidx + N_EDGES;
    float* res = (float*)d_out;

    // workspace layout
    char* ws = (char*)d_ws;
    int* cnt     = (int*)ws;  ws += (size_t)N_NODES * sizeof(int);
    int* row_ptr = (int*)ws;  ws += (size_t)(N_NODES + 1) * sizeof(int);
    int* fill    = (int*)ws;  ws += (size_t)N_NODES * sizeof(int);
    int* packed  = (int*)ws;  ws += (size_t)N_EDGES * sizeof(int);
    int* bsum    = (int*)ws;  ws += (size_t)SCAN_NBLK * sizeof(int);
    ws = (char*)(((uintptr_t)ws + 255) & ~(uintptr_t)255);
    float* x0 = (float*)ws;   ws += (size_t)N_NODES * EMBED_DIM * sizeof(float);
    float* x1 = (float*)ws;

    hipMemsetAsync(cnt,  0, (size_t)N_NODES * sizeof(int), stream);
    hipMemsetAsync(fill, 0, (size_t)N_NODES * sizeof(int), stream);

    const int eblocks = (N_EDGES + 255) / 256;
    hist_kernel<<<eblocks, 256, 0, stream>>>(head, cnt, N_EDGES);
    scan_part <<<SCAN_NBLK, 256, 0, stream>>>(cnt, bsum, N_NODES);
    scan_bsum <<<1, 512, 0, stream>>>(bsum, SCAN_NBLK);
    scan_final<<<SCAN_NBLK, 256, 0, stream>>>(cnt, bsum, row_ptr, N_NODES);
    fill_kernel<<<eblocks, 256, 0, stream>>>(head, tail, etype, row_ptr, fill, packed, N_EDGES);

    // one wave per node
    const int nthreads = N_NODES * 64;
    const int nblocks  = (nthreads + 255) / 256;
    hop_kernel<true ><<<nblocks, 256, 0, stream>>>(ego, rel, row_ptr, packed, ego, x0, res, N_NODES);
    hop_kernel<false><<<nblocks, 256, 0, stream>>>(x0,  rel, row_ptr, packed, nullptr, x1, res, N_NODES);
    hop_kernel<false><<<nblocks, 256, 0, stream>>>(x1,  rel, row_ptr, packed, nullptr, x0, res, N_NODES);
}

// Round 8
// 266.393 us; speedup vs baseline: 1.8207x; 1.2395x over previous
//
#include <hip/hip_runtime.h>

#define N_NODES 100000
#define N_EDGES 600000
#define EMBED_DIM 128
#define EPSF 1e-12f

#define SCAN_NBLK ((N_NODES + 255) / 256)   // 391

// ---------------- CSR build ----------------

__global__ void hist_kernel(const int* __restrict__ head, int* __restrict__ cnt, int E) {
    int e = blockIdx.x * blockDim.x + threadIdx.x;
    if (e < E) atomicAdd(&cnt[head[e]], 1);
}

// Pass 1: per-block sums of cnt
__global__ void scan_part(const int* __restrict__ cnt, int* __restrict__ bsum, int N) {
    __shared__ int lds[256];
    const int t = threadIdx.x;
    const int i = blockIdx.x * 256 + t;
    lds[t] = (i < N) ? cnt[i] : 0;
    __syncthreads();
    for (int off = 128; off; off >>= 1) {
        if (t < off) lds[t] += lds[t + off];
        __syncthreads();
    }
    if (t == 0) bsum[blockIdx.x] = lds[0];
}

// Pass 2: single small block turns bsum into exclusive block offsets (nb <= 512)
__global__ void scan_bsum(int* __restrict__ bsum, int nb) {
    __shared__ int lds[512];
    const int t = threadIdx.x;
    const int v = (t < nb) ? bsum[t] : 0;
    lds[t] = v;
    __syncthreads();
    for (int off = 1; off < 512; off <<= 1) {
        int u = (t >= off) ? lds[t - off] : 0;
        __syncthreads();
        lds[t] += u;
        __syncthreads();
    }
    if (t < nb) bsum[t] = lds[t] - v;   // exclusive
}

// Pass 3: block-local exclusive scan + block offset -> row_ptr
__global__ void scan_final(const int* __restrict__ cnt, const int* __restrict__ bsum,
                           int* __restrict__ row_ptr, int N) {
    __shared__ int lds[256];
    const int t = threadIdx.x;
    const int i = blockIdx.x * 256 + t;
    const int v = (i < N) ? cnt[i] : 0;
    lds[t] = v;
    __syncthreads();
    for (int off = 1; off < 256; off <<= 1) {
        int u = (t >= off) ? lds[t - off] : 0;
        __syncthreads();
        lds[t] += u;
        __syncthreads();
    }
    const int excl = lds[t] - v + bsum[blockIdx.x];
    if (i < N) row_ptr[i] = excl;
    if (i == N - 1) row_ptr[N] = excl + v;
}

// Scatter each edge into its CSR slot as packed (tail | rel<<20).
__global__ void fill_kernel(const int* __restrict__ head, const int* __restrict__ tail,
                            const int* __restrict__ etype, const int* __restrict__ row_ptr,
                            int* __restrict__ fill, int* __restrict__ packed, int E) {
    int e = blockIdx.x * blockDim.x + threadIdx.x;
    if (e < E) {
        int h    = head[e];
        int slot = row_ptr[h] + atomicAdd(&fill[h], 1);
        packed[slot] = tail[e] | (etype[e] << 20);
    }
}

// ---------------- fused hop ----------------
// One wave per node. float4 granularity: lane = 32*h + q, q = float4 slot (0..31),
// h = edge parity (0/1) -> two edges processed per loop iteration.
// packed entries preloaded one-per-lane and broadcast via __shfl (no in-loop
// dependent packed load -> gathers pipeline freely).

template <bool FIRST>
__global__ __launch_bounds__(256) void hop_kernel(
    const float* __restrict__ x, const float* __restrict__ rel,
    const int* __restrict__ row_ptr, const int* __restrict__ packed,
    const float* __restrict__ base,   // ego (FIRST only)
    float* __restrict__ xn, float* __restrict__ res, int N) {

    const int wid  = (int)((blockIdx.x * blockDim.x + threadIdx.x) >> 6);
    const int lane = threadIdx.x & 63;
    if (wid >= N) return;

    const int beg = row_ptr[wid];
    const int deg = row_ptr[wid + 1] - beg;

    const int q = lane & 31;   // float4 slot within the 128-dim row
    const int h = lane >> 5;   // which edge of the pair

    const float4* __restrict__ x4   = (const float4*)x;
    const float4* __restrict__ rel4 = (const float4*)rel;

    // preload up to 64 packed entries, one per lane (coalesced)
    const int pv = (lane < deg) ? packed[beg + lane] : 0;

    float4 acc = make_float4(0.f, 0.f, 0.f, 0.f);
    const int d0 = min(deg, 64);
    for (int e = h; e < d0; e += 2) {
        const int p = __shfl(pv, e, 64);
        const int t = p & 0xFFFFF;
        const int r = p >> 20;
        const float4 xv = x4[t * 32 + q];
        const float4 rv = rel4[r * 32 + q];
        acc.x = fmaf(xv.x, rv.x, acc.x);
        acc.y = fmaf(xv.y, rv.y, acc.y);
        acc.z = fmaf(xv.z, rv.z, acc.z);
        acc.w = fmaf(xv.w, rv.w, acc.w);
    }
    // rare tail: degree > 64 (direct loads)
    for (int e = 64 + h; e < deg; e += 2) {
        const int p = packed[beg + e];
        const int t = p & 0xFFFFF;
        const int r = p >> 20;
        const float4 xv = x4[t * 32 + q];
        const float4 rv = rel4[r * 32 + q];
        acc.x = fmaf(xv.x, rv.x, acc.x);
        acc.y = fmaf(xv.y, rv.y, acc.y);
        acc.z = fmaf(xv.z, rv.z, acc.z);
        acc.w = fmaf(xv.w, rv.w, acc.w);
    }

    // fold the two edge-parity halves
    acc.x += __shfl_xor(acc.x, 32, 64);
    acc.y += __shfl_xor(acc.y, 32, 64);
    acc.z += __shfl_xor(acc.z, 32, 64);
    acc.w += __shfl_xor(acc.w, 32, 64);

    const float inv = 1.0f / (float)max(deg, 1);
    acc.x *= inv; acc.y *= inv; acc.z *= inv; acc.w *= inv;

    // sum of squares across the 32 float4 slots (halves hold identical copies)
    float ss = acc.x * acc.x + acc.y * acc.y + acc.z * acc.z + acc.w * acc.w;
    #pragma unroll
    for (int off = 16; off; off >>= 1) ss += __shfl_xor(ss, off, 64);

    const float scale = 1.0f / fmaxf(sqrtf(ss), EPSF);
    const float4 v = make_float4(acc.x * scale, acc.y * scale,
                                 acc.z * scale, acc.w * scale);

    if (h == 0) {
        const int idx = wid * 32 + q;
        ((float4*)xn)[idx] = v;
        float4* res4 = (float4*)res;
        if (FIRST) {
            const float4 b = ((const float4*)base)[idx];
            res4[idx] = make_float4(b.x + v.x, b.y + v.y, b.z + v.z, b.w + v.w);
        } else {
            const float4 r0 = res4[idx];
            res4[idx] = make_float4(r0.x + v.x, r0.y + v.y, r0.z + v.z, r0.w + v.w);
        }
    }
}

// ---------------- launch ----------------

extern "C" void kernel_launch(void* const* d_in, const int* in_sizes, int n_in,
                              void* d_out, int out_size, void* d_ws, size_t ws_size,
                              hipStream_t stream) {
    const float* ego   = (const float*)d_in[0];
    const int*   eidx  = (const int*)d_in[1];   // [2, E]: row 0 = head, row 1 = tail
    const int*   etype = (const int*)d_in[2];
    const float* rel   = (const float*)d_in[3];
    // d_in[4] = dropout scalar (0 in eval) -> ignored

    const int* head = eidx;
    const int* tail = eidx + N_EDGES;
    float* res = (float*)d_out;

    // workspace layout
    char* ws = (char*)d_ws;
    int* cnt     = (int*)ws;  ws += (size_t)N_NODES * sizeof(int);
    int* row_ptr = (int*)ws;  ws += (size_t)(N_NODES + 1) * sizeof(int);
    int* fill    = (int*)ws;  ws += (size_t)N_NODES * sizeof(int);
    int* packed  = (int*)ws;  ws += (size_t)N_EDGES * sizeof(int);
    int* bsum    = (int*)ws;  ws += (size_t)SCAN_NBLK * sizeof(int);
    ws = (char*)(((uintptr_t)ws + 255) & ~(uintptr_t)255);
    float* x0 = (float*)ws;   ws += (size_t)N_NODES * EMBED_DIM * sizeof(float);
    float* x1 = (float*)ws;

    hipMemsetAsync(cnt,  0, (size_t)N_NODES * sizeof(int), stream);
    hipMemsetAsync(fill, 0, (size_t)N_NODES * sizeof(int), stream);

    const int eblocks = (N_EDGES + 255) / 256;
    hist_kernel<<<eblocks, 256, 0, stream>>>(head, cnt, N_EDGES);
    scan_part <<<SCAN_NBLK, 256, 0, stream>>>(cnt, bsum, N_NODES);
    scan_bsum <<<1, 512, 0, stream>>>(bsum, SCAN_NBLK);
    scan_final<<<SCAN_NBLK, 256, 0, stream>>>(cnt, bsum, row_ptr, N_NODES);
    fill_kernel<<<eblocks, 256, 0, stream>>>(head, tail, etype, row_ptr, fill, packed, N_EDGES);

    // one wave per node
    const int nthreads = N_NODES * 64;
    const int nblocks  = (nthreads + 255) / 256;
    hop_kernel<true ><<<nblocks, 256, 0, stream>>>(ego, rel, row_ptr, packed, ego, x0, res, N_NODES);
    hop_kernel<false><<<nblocks, 256, 0, stream>>>(x0,  rel, row_ptr, packed, nullptr, x1, res, N_NODES);
    hop_kernel<false><<<nblocks, 256, 0, stream>>>(x1,  rel, row_ptr, packed, nullptr, x0, res, N_NODES);
}